// Round 3
// baseline (498.214 us; speedup 1.0000x reference)
//
#include <hip/hip_runtime.h>
#include <hip/hip_bf16.h>

typedef _Float16 half8 __attribute__((ext_vector_type(8)));
typedef float f32x4 __attribute__((ext_vector_type(4)));

#define KC 32
#define DD 128
#define LL 4
#define NCOL 192      // 32 q-cols + 32 r-cols + 128 z-cols
#define NBLK 768      // 3 blocks/CU (LDS-capped at 48KB/block)
#define NSLOT (NBLK*4)

// ---------------------------------------------------------------------------
// Kernel A (1 block): Woodbury factorization per component.
// Writes Ri (32x4x4) + h (32x4) + folded const c (32) to workspace.
// Slot packing for phase-1 partials (16 floats):
//  0..9  = lower-tri of L in (l,m) order
//  10..13= c[l] = sum_d MU*iD*A[:,l]
//  14    = t_const = sum_d iD*MU^2
//  15    = sum_d log(D^2)
// ---------------------------------------------------------------------------
__global__ __launch_bounds__(256) void mfa_woodbury(
    const float* __restrict__ MU, const float* __restrict__ A,
    const float* __restrict__ D, const float* __restrict__ PI,
    float* __restrict__ wsc, float* __restrict__ wsh, float* __restrict__ wsr)
{
  __shared__ float sPart[KC][8][16];
  const int tid = threadIdx.x;
  const int k = tid >> 3;        // 0..31
  const int sub = tid & 7;       // 0..7 -> each handles 16 d's

  // phase 1: partial accumulation
  {
    float p[16];
#pragma unroll
    for (int i = 0; i < 16; ++i) p[i] = 0.f;
    const int d0 = sub * 16;
#pragma unroll 4
    for (int di = 0; di < 16; ++di) {
      const int d = d0 + di;
      const float Dv = D[k*DD + d];
      const float id = 1.0f/(Dv*Dv);
      const float mu = MU[k*DD + d];
      float a[LL];
#pragma unroll
      for (int l = 0; l < LL; ++l) a[l] = A[(k*DD + d)*LL + l];
      int s = 0;
#pragma unroll
      for (int l = 0; l < LL; ++l) {
#pragma unroll
        for (int m2 = 0; m2 <= l; ++m2) { p[s] += a[l]*id*a[m2]; ++s; }
        p[10 + l] += mu*id*a[l];
      }
      p[14] += id*mu*mu;
      p[15] += __logf(Dv*Dv);
    }
#pragma unroll
    for (int i = 0; i < 16; ++i) sPart[k][sub][i] = p[i];
  }
  __syncthreads();

  if (tid < KC) {
    const int kk = tid;
    float p[16];
#pragma unroll
    for (int i = 0; i < 16; ++i) p[i] = 0.f;
    for (int s = 0; s < 8; ++s)
#pragma unroll
      for (int i = 0; i < 16; ++i) p[i] += sPart[kk][s][i];

    // unpack L (lower)
    float Lm[LL][LL];
    {
      int s = 0;
      for (int l = 0; l < LL; ++l)
        for (int m2 = 0; m2 <= l; ++m2) { Lm[l][m2] = p[s]; ++s; }
    }
    for (int l = 0; l < LL; ++l) Lm[l][l] += 1.0f;
    float c[LL];
    for (int l = 0; l < LL; ++l) c[l] = p[10 + l];
    const float t_const  = p[14];
    const float sumlogD2 = p[15];

    // Cholesky: L = Lo * Lo^T  (lower)
    float Lo[LL][LL];
    for (int i = 0; i < LL; ++i)
      for (int j = 0; j < LL; ++j) Lo[i][j] = 0.f;
    for (int i = 0; i < LL; ++i) {
      float s = Lm[i][i];
      for (int m2 = 0; m2 < i; ++m2) s -= Lo[i][m2]*Lo[i][m2];
      Lo[i][i] = sqrtf(s);
      for (int j = i + 1; j < LL; ++j) {
        float t = Lm[j][i];
        for (int m2 = 0; m2 < i; ++m2) t -= Lo[j][m2]*Lo[i][m2];
        Lo[j][i] = t / Lo[i][i];
      }
    }
    // Ri = Lo^{-1} (lower). term2 = |Ri y|^2.
    float Ri[LL][LL];
    for (int i = 0; i < LL; ++i)
      for (int j = 0; j < LL; ++j) Ri[i][j] = 0.f;
    for (int i = 0; i < LL; ++i) {
      Ri[i][i] = 1.0f/Lo[i][i];
      for (int j = 0; j < i; ++j) {
        float s = 0.f;
        for (int m2 = j; m2 < i; ++m2) s += Lo[i][m2]*Ri[m2][j];
        Ri[i][j] = -s / Lo[i][i];
      }
    }
    for (int i = 0; i < LL; ++i)
      for (int j = 0; j < LL; ++j) wsr[kk*16 + i*4 + j] = Ri[i][j];
    // h = Ri c
    for (int l = 0; l < LL; ++l) {
      float s = 0.f;
      for (int m2 = 0; m2 <= l; ++m2) s += Ri[l][m2]*c[m2];
      wsh[kk*LL + l] = s;
    }
    float logdetL = 0.f;
    for (int i = 0; i < LL; ++i) logdetL += __logf(Lo[i][i]);
    logdetL *= 2.0f;
    const float dlog2pi = 235.24826473f;  // 128*log(2*pi)
    wsc[kk] = PI[kk] - 0.5f*(dlog2pi + logdetL + sumlogD2) - 0.5f*t_const;
  }
}

// ---------------------------------------------------------------------------
// Kernel B (96 blocks): weight matrix in MFMA B-fragment order, fp16.
// idx = (t<<11) + (s<<9) + (lane<<3) + j8
// element = W[col = t*16 + (lane&15)][dd = s*32 + (lane>>4)*8 + j8]
// ---------------------------------------------------------------------------
__global__ __launch_bounds__(256) void mfa_weights(
    const float* __restrict__ MU, const float* __restrict__ A,
    const float* __restrict__ D, const float* __restrict__ wsr,
    _Float16* __restrict__ wsw)
{
  const int idx = (int)blockIdx.x*256 + (int)threadIdx.x;   // < 24576
  const int j8   = idx & 7;
  const int lane = (idx >> 3) & 63;
  const int s    = (idx >> 9) & 3;
  const int t    = idx >> 11;
  const int col  = t*16 + (lane & 15);
  const int dd   = s*32 + ((lane >> 4) << 3) + j8;
  float v;
  if (col < 32) {                       // q columns: iD (paired with x^2 frags)
    const float Dv = D[col*DD + dd];
    v = 1.0f/(Dv*Dv);
  } else if (col < 64) {                // r columns: iD*MU
    const int kk = col - 32;
    const float Dv = D[kk*DD + dd];
    v = MU[kk*DD + dd]/(Dv*Dv);
  } else {                              // z columns: G = iD * (A @ Ri^T)
    const int kk = (col - 64) >> 2, l = (col - 64) & 3;
    const float Dv = D[kk*DD + dd];
    const float id = 1.0f/(Dv*Dv);
    float s2 = 0.f;
    for (int m2 = 0; m2 <= l; ++m2)
      s2 += A[(kk*DD + dd)*LL + m2] * wsr[kk*16 + l*4 + m2];
    v = id*s2;
  }
  wsw[idx] = (_Float16)v;
}

// ---------------------------------------------------------------------------
// Main kernel: 4 waves/block, each wave owns a 16-row tile per iteration.
// Shuffle epilogue (no in-loop barriers); register prefetch of next tile's x.
// ---------------------------------------------------------------------------
__global__ __launch_bounds__(256, 3) void mfa_main(
    const float* __restrict__ x, const _Float16* __restrict__ wsw,
    const float* __restrict__ wsc, const float* __restrict__ wsh,
    float* __restrict__ out, int N, int ntiles, int iters)
{
  __shared__ int4 sWbuf[3072];                    // 48 KB weights (fragment order)
  const int tid = threadIdx.x;

  {
    const int4* src = (const int4*)wsw;
    for (int i = tid; i < 3072; i += 256) sWbuf[i] = src[i];
  }

  const half8* sW8 = (const half8*)sWbuf;
  const int wv = tid >> 6, lane = tid & 63;
  const int m = lane & 15, g = lane >> 4;
  const int q = m >> 2;
  const int gbase = lane & 48;                    // g*16

  // per-lane constants: c0/c1 pair with k=m and k=m+16; hh[j] = h[(j*16+m)]
  const float c0 = wsc[m];
  const float c1 = wsc[16 + m];
  float hh[8];
#pragma unroll
  for (int j = 0; j < 8; ++j) hh[j] = wsh[j*16 + m];

  __syncthreads();   // weights visible to all waves

  int tile = (int)blockIdx.x*4 + wv;              // this wave's slot
  const int tmax = ntiles - 1;

  // preload tile 0's x rows (8 x float4 = 32 B/lane)
  float4 xv[8];
  {
    const int t0 = tile < ntiles ? tile : tmax;
    const float* xr = x + (size_t)(t0*16 + m)*DD + g*8;
#pragma unroll
    for (int s = 0; s < 4; ++s) {
      xv[2*s]     = *(const float4*)(xr + s*32);
      xv[2*s + 1] = *(const float4*)(xr + s*32 + 4);
    }
  }

  for (int it = 0; it < iters; ++it) {
    const int tnext = tile + NSLOT;
    // ---- prefetch next tile's x into registers ----
    float4 xvn[8];
    {
      const int tp = tnext < ntiles ? tnext : tmax;
      const float* xrn = x + (size_t)(tp*16 + m)*DD + g*8;
#pragma unroll
      for (int s = 0; s < 4; ++s) {
        xvn[2*s]     = *(const float4*)(xrn + s*32);
        xvn[2*s + 1] = *(const float4*)(xrn + s*32 + 4);
      }
    }

    // ---- MFMA over current tile: fragments built per K-step ----
    f32x4 acc[12];
#pragma unroll
    for (int t = 0; t < 12; ++t)
#pragma unroll
      for (int r = 0; r < 4; ++r) acc[t][r] = 0.f;

#pragma unroll
    for (int s = 0; s < 4; ++s) {
      const float4 v0 = xv[2*s], v1 = xv[2*s + 1];
      half8 h, h2;
      h[0] = (_Float16)v0.x; h[1] = (_Float16)v0.y;
      h[2] = (_Float16)v0.z; h[3] = (_Float16)v0.w;
      h[4] = (_Float16)v1.x; h[5] = (_Float16)v1.y;
      h[6] = (_Float16)v1.z; h[7] = (_Float16)v1.w;
      h2[0] = (_Float16)(v0.x*v0.x); h2[1] = (_Float16)(v0.y*v0.y);
      h2[2] = (_Float16)(v0.z*v0.z); h2[3] = (_Float16)(v0.w*v0.w);
      h2[4] = (_Float16)(v1.x*v1.x); h2[5] = (_Float16)(v1.y*v1.y);
      h2[6] = (_Float16)(v1.z*v1.z); h2[7] = (_Float16)(v1.w*v1.w);
#pragma unroll
      for (int t = 0; t < 12; ++t) {
        const half8 b = sW8[(t*4 + s)*64 + lane];
        acc[t] = __builtin_amdgcn_mfma_f32_16x16x32_f16(
            (t < 2) ? h2 : h, b, acc[t], 0, 0, 0);
      }
    }

    // ---- shuffle epilogue ----
    // C layout: row = g*4 + r, col(of tile t) = m  (k = t*16+m).
    float vp0[4], vp1[4];
#pragma unroll
    for (int r = 0; r < 4; ++r) {
      vp0[r] = acc[2][r] - 0.5f*acc[0][r] + c0;
      vp1[r] = acc[3][r] - 0.5f*acc[1][r] + c1;
    }
    // term2: lane holds z[k = j*4 + q][l = m&3] for j=0..7; quad-reduce over l.
    float t2[8][4];
#pragma unroll
    for (int j = 0; j < 8; ++j)
#pragma unroll
      for (int r = 0; r < 4; ++r) {
        float e = acc[j + 4][r] - hh[j];
        e = e*e;
        e += __shfl_xor(e, 1);
        e += __shfl_xor(e, 2);
        t2[j][r] = e;
      }
    // gather u for this lane's 8 k's (k = 4*j + q), logsumexp over 32 k.
    float res[4];
#pragma unroll
    for (int r = 0; r < 4; ++r) {
      float v[8];
#pragma unroll
      for (int jj = 0; jj < 4; ++jj) {
        const int src = gbase + 4*jj + q;
        v[jj]     = __shfl(vp0[r], src) + 0.5f*t2[jj][r];
        v[jj + 4] = __shfl(vp1[r], src) + 0.5f*t2[jj + 4][r];
      }
      float mx = v[0];
#pragma unroll
      for (int i = 1; i < 8; ++i) mx = fmaxf(mx, v[i]);
      mx = fmaxf(mx, __shfl_xor(mx, 4));
      mx = fmaxf(mx, __shfl_xor(mx, 8));
      float sum = 0.f;
#pragma unroll
      for (int i = 0; i < 8; ++i) sum += __expf(v[i] - mx);
      sum += __shfl_xor(sum, 4);
      sum += __shfl_xor(sum, 8);
      res[r] = mx + __logf(sum);
    }
    if (m == 0 && tile < ntiles) {
      float4 o; o.x = res[0]; o.y = res[1]; o.z = res[2]; o.w = res[3];
      *(float4*)(out + (size_t)tile*16 + g*4) = o;
    }

    // rotate pipeline
#pragma unroll
    for (int i = 0; i < 8; ++i) xv[i] = xvn[i];
    tile = tnext;
  }
}

extern "C" void kernel_launch(void* const* d_in, const int* in_sizes, int n_in,
                              void* d_out, int out_size, void* d_ws, size_t ws_size,
                              hipStream_t stream) {
  const float* x  = (const float*)d_in[0];
  const float* MU = (const float*)d_in[1];
  const float* A  = (const float*)d_in[2];
  const float* D  = (const float*)d_in[3];
  const float* PI = (const float*)d_in[4];
  float* out = (float*)d_out;

  const int N = in_sizes[0] / DD;
  _Float16* wsw = (_Float16*)d_ws;
  float* wsc = (float*)((char*)d_ws + (size_t)NCOL*DD*sizeof(_Float16)); // +49152
  float* wsh = wsc + KC;            // 128 floats
  float* wsr = wsh + KC*LL;         // 512 floats (Ri)

  hipLaunchKernelGGL(mfa_woodbury, dim3(1), dim3(256), 0, stream,
                     MU, A, D, PI, wsc, wsh, wsr);
  hipLaunchKernelGGL(mfa_weights, dim3(96), dim3(256), 0, stream,
                     MU, A, D, wsr, wsw);

  const int ntiles = (N + 15) / 16;
  const int iters  = (ntiles + NSLOT - 1) / NSLOT;
  hipLaunchKernelGGL(mfa_main, dim3(NBLK), dim3(256), 0, stream,
                     x, wsw, wsc, wsh, out, N, ntiles, iters);
}

// Round 5
// 377.278 us; speedup vs baseline: 1.3205x; 1.3205x over previous
//
#include <hip/hip_runtime.h>
#include <hip/hip_bf16.h>

typedef _Float16 half8  __attribute__((ext_vector_type(8)));
typedef _Float16 half2v __attribute__((ext_vector_type(2)));
typedef float    f32x16 __attribute__((ext_vector_type(16)));

#define KC 32
#define DD 128
#define LL 4
#define NCOL 192      // 32 q-cols + 32 r-cols + 128 z-cols
#define NBLK 512      // 2 blocks/CU resident (iter loop over tiles)
#define WPB 4
#define NSLOT (NBLK*WPB)

// ---------------------------------------------------------------------------
// Kernel A (1 block): Woodbury factorization per component.
// Writes Ri (32x4x4) + h (32x4) + folded const c (32) to workspace.
// ---------------------------------------------------------------------------
__global__ __launch_bounds__(256) void mfa_woodbury(
    const float* __restrict__ MU, const float* __restrict__ A,
    const float* __restrict__ D, const float* __restrict__ PI,
    float* __restrict__ wsc, float* __restrict__ wsh, float* __restrict__ wsr)
{
  __shared__ float sPart[KC][8][16];
  const int tid = threadIdx.x;
  const int k = tid >> 3;
  const int sub = tid & 7;

  {
    float p[16];
#pragma unroll
    for (int i = 0; i < 16; ++i) p[i] = 0.f;
    const int d0 = sub * 16;
#pragma unroll 4
    for (int di = 0; di < 16; ++di) {
      const int d = d0 + di;
      const float Dv = D[k*DD + d];
      const float id = 1.0f/(Dv*Dv);
      const float mu = MU[k*DD + d];
      float a[LL];
#pragma unroll
      for (int l = 0; l < LL; ++l) a[l] = A[(k*DD + d)*LL + l];
      int s = 0;
#pragma unroll
      for (int l = 0; l < LL; ++l) {
#pragma unroll
        for (int m2 = 0; m2 <= l; ++m2) { p[s] += a[l]*id*a[m2]; ++s; }
        p[10 + l] += mu*id*a[l];
      }
      p[14] += id*mu*mu;
      p[15] += __logf(Dv*Dv);
    }
#pragma unroll
    for (int i = 0; i < 16; ++i) sPart[k][sub][i] = p[i];
  }
  __syncthreads();

  if (tid < KC) {
    const int kk = tid;
    float p[16];
#pragma unroll
    for (int i = 0; i < 16; ++i) p[i] = 0.f;
    for (int s = 0; s < 8; ++s)
#pragma unroll
      for (int i = 0; i < 16; ++i) p[i] += sPart[kk][s][i];

    float Lm[LL][LL];
    {
      int s = 0;
      for (int l = 0; l < LL; ++l)
        for (int m2 = 0; m2 <= l; ++m2) { Lm[l][m2] = p[s]; ++s; }
    }
    for (int l = 0; l < LL; ++l) Lm[l][l] += 1.0f;
    float c[LL];
    for (int l = 0; l < LL; ++l) c[l] = p[10 + l];
    const float t_const  = p[14];
    const float sumlogD2 = p[15];

    float Lo[LL][LL];
    for (int i = 0; i < LL; ++i)
      for (int j = 0; j < LL; ++j) Lo[i][j] = 0.f;
    for (int i = 0; i < LL; ++i) {
      float s = Lm[i][i];
      for (int m2 = 0; m2 < i; ++m2) s -= Lo[i][m2]*Lo[i][m2];
      Lo[i][i] = sqrtf(s);
      for (int j = i + 1; j < LL; ++j) {
        float t = Lm[j][i];
        for (int m2 = 0; m2 < i; ++m2) t -= Lo[j][m2]*Lo[i][m2];
        Lo[j][i] = t / Lo[i][i];
      }
    }
    float Ri[LL][LL];
    for (int i = 0; i < LL; ++i)
      for (int j = 0; j < LL; ++j) Ri[i][j] = 0.f;
    for (int i = 0; i < LL; ++i) {
      Ri[i][i] = 1.0f/Lo[i][i];
      for (int j = 0; j < i; ++j) {
        float s = 0.f;
        for (int m2 = j; m2 < i; ++m2) s += Lo[i][m2]*Ri[m2][j];
        Ri[i][j] = -s / Lo[i][i];
      }
    }
    for (int i = 0; i < LL; ++i)
      for (int j = 0; j < LL; ++j) wsr[kk*16 + i*4 + j] = Ri[i][j];
    for (int l = 0; l < LL; ++l) {
      float s = 0.f;
      for (int m2 = 0; m2 <= l; ++m2) s += Ri[l][m2]*c[m2];
      wsh[kk*LL + l] = s;
    }
    float logdetL = 0.f;
    for (int i = 0; i < LL; ++i) logdetL += __logf(Lo[i][i]);
    logdetL *= 2.0f;
    const float dlog2pi = 235.24826473f;  // 128*log(2*pi)
    wsc[kk] = PI[kk] - 0.5f*(dlog2pi + logdetL + sumlogD2) - 0.5f*t_const;
  }
}

// ---------------------------------------------------------------------------
// Kernel B (96 blocks): weight matrix in 32x32x16 MFMA B-fragment order.
// idx = ((t*8+s)*64 + lane)*8 + j
// element = W[col = 32t + (lane&31)][dd = 16s + 8*(lane>>5) + j]
// ---------------------------------------------------------------------------
__global__ __launch_bounds__(256) void mfa_weights(
    const float* __restrict__ MU, const float* __restrict__ A,
    const float* __restrict__ D, const float* __restrict__ wsr,
    _Float16* __restrict__ wsw)
{
  const int idx = (int)blockIdx.x*256 + (int)threadIdx.x;   // < 24576
  const int j    = idx & 7;
  const int lane = (idx >> 3) & 63;
  const int s    = (idx >> 9) & 7;
  const int t    = idx >> 12;
  const int col  = t*32 + (lane & 31);
  const int dd   = s*16 + ((lane >> 5) << 3) + j;
  float v;
  if (col < 32) {                       // q columns: iD (pairs with x^2 frags)
    const float Dv = D[col*DD + dd];
    v = 1.0f/(Dv*Dv);
  } else if (col < 64) {                // r columns: iD*MU
    const int kk = col - 32;
    const float Dv = D[kk*DD + dd];
    v = MU[kk*DD + dd]/(Dv*Dv);
  } else {                              // z columns: G = iD * (A @ Ri^T)
    const int kk = (col - 64) >> 2, l = (col - 64) & 3;
    const float Dv = D[kk*DD + dd];
    const float id = 1.0f/(Dv*Dv);
    float s2 = 0.f;
    for (int m2 = 0; m2 <= l; ++m2)
      s2 += A[(kk*DD + dd)*LL + m2] * wsr[kk*16 + l*4 + m2];
    v = id*s2;
  }
  wsw[idx] = (_Float16)v;
}

// ---------------------------------------------------------------------------
// helpers
// ---------------------------------------------------------------------------
__device__ inline half2v pkrtz(float a, float b) {
  return __builtin_bit_cast(half2v, __builtin_amdgcn_cvt_pkrtz(a, b));
}
__device__ inline half2v shx2(half2v v, int d) {
  int i = __builtin_bit_cast(int, v);
  i = __shfl_xor(i, d);
  return __builtin_bit_cast(half2v, i);
}
__device__ inline half2v shl2(half2v v, int src) {
  int i = __builtin_bit_cast(int, v);
  i = __shfl(i, src);
  return __builtin_bit_cast(half2v, i);
}
__device__ inline half2v pmax2(half2v a, half2v b) {
  half2v r;
  r[0] = a[0] > b[0] ? a[0] : b[0];
  r[1] = a[1] > b[1] ? a[1] : b[1];
  return r;
}
__device__ inline half2v sel8(const half2v* p, int i) {
  half2v a = (i & 1) ? p[1] : p[0];
  half2v b = (i & 1) ? p[3] : p[2];
  half2v c = (i & 1) ? p[5] : p[4];
  half2v d = (i & 1) ? p[7] : p[6];
  half2v e = (i & 2) ? b : a;
  half2v f = (i & 2) ? d : c;
  return (i & 4) ? f : e;
}

// ---------------------------------------------------------------------------
// Main kernel: 4 waves/block, each wave owns a 32-row tile per iteration.
// 32x32x16 MFMA; epilogue in C-layout (col = lane = component k): packed-fp16
// butterflies, no LDS staging, no in-loop barriers.
// ---------------------------------------------------------------------------
__global__ __launch_bounds__(256, 2) void mfa_main(
    const float* __restrict__ x, const _Float16* __restrict__ wsw,
    const float* __restrict__ wsc, const float* __restrict__ wsh,
    float* __restrict__ out, int N, int ntiles, int iters)
{
  __shared__ int4 sWbuf[3072];                    // 48 KB weights (fragment order)
  const int tid = threadIdx.x;
  {
    const int4* src = (const int4*)wsw;
    for (int i = tid; i < 3072; i += 256) sWbuf[i] = src[i];
  }
  const half8* sW8 = (const half8*)sWbuf;

  const int wv = tid >> 6, lane = tid & 63;
  const int c = lane & 31;                        // component/col index
  const int h = lane >> 5;                        // row-half
  const float cc = wsc[c];
  float hz[4];
#pragma unroll
  for (int zt = 0; zt < 4; ++zt) hz[zt] = wsh[(8*zt + (c >> 2))*4 + (c & 3)];
  // transport source lane: t2 for k=c lives (replicated per quad) where
  // (src&31)>>2 == c&7; keep within own 32-lane half.
  const int srcl = (lane & 32) | ((c & 7) << 2) | (c & 3);

  __syncthreads();   // weights visible

  for (int it = 0; it < iters; ++it) {
    const int tile = it*NSLOT + (int)blockIdx.x*WPB + wv;
    if (tile >= ntiles) continue;

    int row = tile*32 + c;
    if (row >= N) row = N - 1;
    const float* xr = x + (size_t)row*DD + h*8;

    f32x16 acc[6];
#pragma unroll
    for (int t = 0; t < 6; ++t)
#pragma unroll
      for (int r = 0; r < 16; ++r) acc[t][r] = 0.f;

    // K-loop in two batches of 4 k-steps (keeps xv liveness at 32 VGPRs)
#pragma unroll
    for (int half_b = 0; half_b < 2; ++half_b) {
      float4 xv[8];
#pragma unroll
      for (int s = 0; s < 4; ++s) {
        const int ss = half_b*4 + s;
        xv[2*s]     = *(const float4*)(xr + ss*16);
        xv[2*s + 1] = *(const float4*)(xr + ss*16 + 4);
      }
#pragma unroll
      for (int s = 0; s < 4; ++s) {
        const int ss = half_b*4 + s;
        const float4 a = xv[2*s], b = xv[2*s + 1];
        union { half8 v; half2v p[4]; } hx, hx2;
        hx.p[0] = pkrtz(a.x, a.y);
        hx.p[1] = pkrtz(a.z, a.w);
        hx.p[2] = pkrtz(b.x, b.y);
        hx.p[3] = pkrtz(b.z, b.w);
        hx2.v = hx.v * hx.v;                       // packed f16 squares
        acc[0] = __builtin_amdgcn_mfma_f32_32x32x16_f16(
            hx2.v, sW8[(0*8 + ss)*64 + lane], acc[0], 0, 0, 0);
#pragma unroll
        for (int t = 1; t < 6; ++t)
          acc[t] = __builtin_amdgcn_mfma_f32_32x32x16_f16(
              hx.v, sW8[(t*8 + ss)*64 + lane], acc[t], 0, 0, 0);
      }
    }

    // ---- epilogue (C layout: col = c = component k; 16 regs = 16 rows) ----
    // u(row r, k=c) with folded constant
    float vp[16];
#pragma unroll
    for (int r = 0; r < 16; ++r)
      vp[r] = acc[1][r] - 0.5f*acc[0][r] + cc;

    // t2: e^2 packed, quad-reduce over l (lanes c&3)
    half2v tq[4][8];
#pragma unroll
    for (int zt = 0; zt < 4; ++zt)
#pragma unroll
      for (int i = 0; i < 8; ++i) {
        const float e0 = acc[2 + zt][2*i]     - hz[zt];
        const float e1 = acc[2 + zt][2*i + 1] - hz[zt];
        half2v p = pkrtz(e0*e0, e1*e1);
        p = p + shx2(p, 1);
        p = p + shx2(p, 2);
        tq[zt][i] = p;
      }
    // transport t2 to its k-owner lane (k = c): pull all 4 tile arrays from
    // srcl, select by zt* = c>>3
#pragma unroll
    for (int i = 0; i < 8; ++i) {
      half2v b0 = shl2(tq[0][i], srcl);
      half2v b1 = shl2(tq[1][i], srcl);
      half2v b2 = shl2(tq[2][i], srcl);
      half2v b3 = shl2(tq[3][i], srcl);
      half2v m01 = (c & 8)  ? b1 : b0;
      half2v m23 = (c & 8)  ? b3 : b2;
      half2v st  = (c & 16) ? m23 : m01;
      vp[2*i]     += 0.5f*(float)st[0];
      vp[2*i + 1] += 0.5f*(float)st[1];
    }

    // per-row max over the 32 k-lanes (packed fp16 butterfly; exactness-safe)
    half2v pm[8];
#pragma unroll
    for (int i = 0; i < 8; ++i)
      pm[i] = pkrtz(vp[2*i], vp[2*i + 1]);
#pragma unroll
    for (int d = 1; d <= 16; d <<= 1)
#pragma unroll
      for (int i = 0; i < 8; ++i) pm[i] = pmax2(pm[i], shx2(pm[i], d));

    // exp + packed sum butterfly
    half2v ps[8];
#pragma unroll
    for (int i = 0; i < 8; ++i) {
      const float e0 = __expf(vp[2*i]     - (float)pm[i][0]);
      const float e1 = __expf(vp[2*i + 1] - (float)pm[i][1]);
      ps[i] = pkrtz(e0, e1);
    }
#pragma unroll
    for (int d = 1; d <= 16; d <<= 1)
#pragma unroll
      for (int i = 0; i < 8; ++i) ps[i] = ps[i] + shx2(ps[i], d);

    // write: lanes c<16 of each half cover the 32 rows
    if (c < 16) {
      const half2v S = sel8(ps, c >> 1);
      const half2v M = sel8(pm, c >> 1);
      const float sum = (c & 1) ? (float)S[1] : (float)S[0];
      const float mx  = (c & 1) ? (float)M[1] : (float)M[0];
      const int rw = tile*32 + (c & 3) + 8*(c >> 2) + 4*h;
      if (rw < N) out[rw] = mx + __logf(sum);
    }
  }
}

extern "C" void kernel_launch(void* const* d_in, const int* in_sizes, int n_in,
                              void* d_out, int out_size, void* d_ws, size_t ws_size,
                              hipStream_t stream) {
  const float* x  = (const float*)d_in[0];
  const float* MU = (const float*)d_in[1];
  const float* A  = (const float*)d_in[2];
  const float* D  = (const float*)d_in[3];
  const float* PI = (const float*)d_in[4];
  float* out = (float*)d_out;

  const int N = in_sizes[0] / DD;
  _Float16* wsw = (_Float16*)d_ws;
  float* wsc = (float*)((char*)d_ws + (size_t)NCOL*DD*sizeof(_Float16)); // +49152
  float* wsh = wsc + KC;            // 128 floats
  float* wsr = wsh + KC*LL;         // 512 floats (Ri)

  hipLaunchKernelGGL(mfa_woodbury, dim3(1), dim3(256), 0, stream,
                     MU, A, D, PI, wsc, wsh, wsr);
  hipLaunchKernelGGL(mfa_weights, dim3(96), dim3(256), 0, stream,
                     MU, A, D, wsr, wsw);

  const int ntiles = (N + 31) / 32;
  const int iters  = (ntiles + NSLOT - 1) / NSLOT;
  hipLaunchKernelGGL(mfa_main, dim3(NBLK), dim3(256), 0, stream,
                     x, wsw, wsc, wsh, out, N, ntiles, iters);
}

// Round 6
// 369.192 us; speedup vs baseline: 1.3495x; 1.0219x over previous
//
#include <hip/hip_runtime.h>
#include <hip/hip_bf16.h>

typedef _Float16 half8  __attribute__((ext_vector_type(8)));
typedef _Float16 half2v __attribute__((ext_vector_type(2)));
typedef float    f32x16 __attribute__((ext_vector_type(16)));

#define KC 32
#define DD 128
#define LL 4
#define NCOL 192      // 32 q-cols + 32 r-cols + 128 z-cols
#define NBLK 768      // 3 blocks/CU resident (48KB LDS each -> 144KB/CU)
#define WPB 4
#define NSLOT (NBLK*WPB)

// ---------------------------------------------------------------------------
// Kernel A (1 block): Woodbury factorization per component.
// Writes Ri (32x4x4) + h (32x4) + folded const c (32) to workspace.
// ---------------------------------------------------------------------------
__global__ __launch_bounds__(256) void mfa_woodbury(
    const float* __restrict__ MU, const float* __restrict__ A,
    const float* __restrict__ D, const float* __restrict__ PI,
    float* __restrict__ wsc, float* __restrict__ wsh, float* __restrict__ wsr)
{
  __shared__ float sPart[KC][8][16];
  const int tid = threadIdx.x;
  const int k = tid >> 3;
  const int sub = tid & 7;

  {
    float p[16];
#pragma unroll
    for (int i = 0; i < 16; ++i) p[i] = 0.f;
    const int d0 = sub * 16;
#pragma unroll 4
    for (int di = 0; di < 16; ++di) {
      const int d = d0 + di;
      const float Dv = D[k*DD + d];
      const float id = 1.0f/(Dv*Dv);
      const float mu = MU[k*DD + d];
      float a[LL];
#pragma unroll
      for (int l = 0; l < LL; ++l) a[l] = A[(k*DD + d)*LL + l];
      int s = 0;
#pragma unroll
      for (int l = 0; l < LL; ++l) {
#pragma unroll
        for (int m2 = 0; m2 <= l; ++m2) { p[s] += a[l]*id*a[m2]; ++s; }
        p[10 + l] += mu*id*a[l];
      }
      p[14] += id*mu*mu;
      p[15] += __logf(Dv*Dv);
    }
#pragma unroll
    for (int i = 0; i < 16; ++i) sPart[k][sub][i] = p[i];
  }
  __syncthreads();

  if (tid < KC) {
    const int kk = tid;
    float p[16];
#pragma unroll
    for (int i = 0; i < 16; ++i) p[i] = 0.f;
    for (int s = 0; s < 8; ++s)
#pragma unroll
      for (int i = 0; i < 16; ++i) p[i] += sPart[kk][s][i];

    float Lm[LL][LL];
    {
      int s = 0;
      for (int l = 0; l < LL; ++l)
        for (int m2 = 0; m2 <= l; ++m2) { Lm[l][m2] = p[s]; ++s; }
    }
    for (int l = 0; l < LL; ++l) Lm[l][l] += 1.0f;
    float c[LL];
    for (int l = 0; l < LL; ++l) c[l] = p[10 + l];
    const float t_const  = p[14];
    const float sumlogD2 = p[15];

    float Lo[LL][LL];
    for (int i = 0; i < LL; ++i)
      for (int j = 0; j < LL; ++j) Lo[i][j] = 0.f;
    for (int i = 0; i < LL; ++i) {
      float s = Lm[i][i];
      for (int m2 = 0; m2 < i; ++m2) s -= Lo[i][m2]*Lo[i][m2];
      Lo[i][i] = sqrtf(s);
      for (int j = i + 1; j < LL; ++j) {
        float t = Lm[j][i];
        for (int m2 = 0; m2 < i; ++m2) t -= Lo[j][m2]*Lo[i][m2];
        Lo[j][i] = t / Lo[i][i];
      }
    }
    float Ri[LL][LL];
    for (int i = 0; i < LL; ++i)
      for (int j = 0; j < LL; ++j) Ri[i][j] = 0.f;
    for (int i = 0; i < LL; ++i) {
      Ri[i][i] = 1.0f/Lo[i][i];
      for (int j = 0; j < i; ++j) {
        float s = 0.f;
        for (int m2 = j; m2 < i; ++m2) s += Lo[i][m2]*Ri[m2][j];
        Ri[i][j] = -s / Lo[i][i];
      }
    }
    for (int i = 0; i < LL; ++i)
      for (int j = 0; j < LL; ++j) wsr[kk*16 + i*4 + j] = Ri[i][j];
    for (int l = 0; l < LL; ++l) {
      float s = 0.f;
      for (int m2 = 0; m2 <= l; ++m2) s += Ri[l][m2]*c[m2];
      wsh[kk*LL + l] = s;
    }
    float logdetL = 0.f;
    for (int i = 0; i < LL; ++i) logdetL += __logf(Lo[i][i]);
    logdetL *= 2.0f;
    const float dlog2pi = 235.24826473f;  // 128*log(2*pi)
    wsc[kk] = PI[kk] - 0.5f*(dlog2pi + logdetL + sumlogD2) - 0.5f*t_const;
  }
}

// ---------------------------------------------------------------------------
// Kernel B (96 blocks): weight matrix in 32x32x16 MFMA B-fragment order.
// idx = ((t*8+s)*64 + lane)*8 + j
// element = W[col = 32t + (lane&31)][dd = 16s + 8*(lane>>5) + j]
// ---------------------------------------------------------------------------
__global__ __launch_bounds__(256) void mfa_weights(
    const float* __restrict__ MU, const float* __restrict__ A,
    const float* __restrict__ D, const float* __restrict__ wsr,
    _Float16* __restrict__ wsw)
{
  const int idx = (int)blockIdx.x*256 + (int)threadIdx.x;   // < 24576
  const int j    = idx & 7;
  const int lane = (idx >> 3) & 63;
  const int s    = (idx >> 9) & 7;
  const int t    = idx >> 12;
  const int col  = t*32 + (lane & 31);
  const int dd   = s*16 + ((lane >> 5) << 3) + j;
  float v;
  if (col < 32) {                       // q columns: iD (pairs with x^2 frags)
    const float Dv = D[col*DD + dd];
    v = 1.0f/(Dv*Dv);
  } else if (col < 64) {                // r columns: iD*MU
    const int kk = col - 32;
    const float Dv = D[kk*DD + dd];
    v = MU[kk*DD + dd]/(Dv*Dv);
  } else {                              // z columns: G = iD * (A @ Ri^T)
    const int kk = (col - 64) >> 2, l = (col - 64) & 3;
    const float Dv = D[kk*DD + dd];
    const float id = 1.0f/(Dv*Dv);
    float s2 = 0.f;
    for (int m2 = 0; m2 <= l; ++m2)
      s2 += A[(kk*DD + dd)*LL + m2] * wsr[kk*16 + l*4 + m2];
    v = id*s2;
  }
  wsw[idx] = (_Float16)v;
}

// ---------------------------------------------------------------------------
// helpers
// ---------------------------------------------------------------------------
__device__ inline half2v pkrtz(float a, float b) {
  return __builtin_bit_cast(half2v, __builtin_amdgcn_cvt_pkrtz(a, b));
}
__device__ inline half2v shx2(half2v v, int d) {        // DS-pipe shuffle
  int i = __builtin_bit_cast(int, v);
  i = __shfl_xor(i, d);
  return __builtin_bit_cast(half2v, i);
}
__device__ inline half2v shl2(half2v v, int src) {      // DS-pipe bpermute
  int i = __builtin_bit_cast(int, v);
  i = __shfl(i, src);
  return __builtin_bit_cast(half2v, i);
}
// DPP cross-lane (VALU pipe, no DS): ctrl is a compile-time constant.
// 0xB1 = quad_perm xor1, 0x4E = quad_perm xor2,
// 0x141 = row_half_mirror (xor7), 0x140 = row_mirror (xor15).
template <int CTRL>
__device__ inline half2v dpp2(half2v v) {
  int i = __builtin_bit_cast(int, v);
  int r = __builtin_amdgcn_update_dpp(i, i, CTRL, 0xF, 0xF, true);
  return __builtin_bit_cast(half2v, r);
}
__device__ inline half2v pmax2(half2v a, half2v b) {
  half2v r;
  r[0] = a[0] > b[0] ? a[0] : b[0];
  r[1] = a[1] > b[1] ? a[1] : b[1];
  return r;
}
__device__ inline half2v sel8(const half2v* p, int i) {
  half2v a = (i & 1) ? p[1] : p[0];
  half2v b = (i & 1) ? p[3] : p[2];
  half2v c = (i & 1) ? p[5] : p[4];
  half2v d = (i & 1) ? p[7] : p[6];
  half2v e = (i & 2) ? b : a;
  half2v f = (i & 2) ? d : c;
  return (i & 4) ? f : e;
}

// ---------------------------------------------------------------------------
// Main kernel: 4 waves/block, each wave owns a 32-row tile per iteration.
// 32x32x16 MFMA; epilogue in C-layout (col = lane = component k). Reductions
// use DPP (VALU) for xor1/2/4/8 and DS only for xor16 + k-owner transport.
// ---------------------------------------------------------------------------
__global__ __launch_bounds__(256, 3) void mfa_main(
    const float* __restrict__ x, const _Float16* __restrict__ wsw,
    const float* __restrict__ wsc, const float* __restrict__ wsh,
    float* __restrict__ out, int N, int ntiles, int iters)
{
  __shared__ int4 sWbuf[3072];                    // 48 KB weights (fragment order)
  const int tid = threadIdx.x;
  {
    const int4* src = (const int4*)wsw;
    for (int i = tid; i < 3072; i += 256) sWbuf[i] = src[i];
  }
  const half8* sW8 = (const half8*)sWbuf;

  const int wv = tid >> 6, lane = tid & 63;
  const int c = lane & 31;                        // component/col index
  const int h = lane >> 5;                        // row-half
  const float cc = wsc[c];
  float hz[4];
#pragma unroll
  for (int zt = 0; zt < 4; ++zt) hz[zt] = wsh[(8*zt + (c >> 2))*4 + (c & 3)];
  // transport source lane: t2 for k=c lives (replicated per quad) where
  // (src&31)>>2 == c&7; keep within own 32-lane half.
  const int srcl = (lane & 32) | ((c & 7) << 2) | (c & 3);

  __syncthreads();   // weights visible

  for (int it = 0; it < iters; ++it) {
    const int tile = it*NSLOT + (int)blockIdx.x*WPB + wv;
    if (tile >= ntiles) continue;

    int row = tile*32 + c;
    if (row >= N) row = N - 1;
    const float* xr = x + (size_t)row*DD + h*8;

    f32x16 acc[6];
#pragma unroll
    for (int t = 0; t < 6; ++t)
#pragma unroll
      for (int r = 0; r < 16; ++r) acc[t][r] = 0.f;

    // K-loop in two batches of 4 k-steps (keeps xv liveness at 32 VGPRs)
#pragma unroll
    for (int half_b = 0; half_b < 2; ++half_b) {
      float4 xv[8];
#pragma unroll
      for (int s = 0; s < 4; ++s) {
        const int ss = half_b*4 + s;
        xv[2*s]     = *(const float4*)(xr + ss*16);
        xv[2*s + 1] = *(const float4*)(xr + ss*16 + 4);
      }
#pragma unroll
      for (int s = 0; s < 4; ++s) {
        const int ss = half_b*4 + s;
        const float4 a = xv[2*s], b = xv[2*s + 1];
        union { half8 v; half2v p[4]; } hx, hx2;
        hx.p[0] = pkrtz(a.x, a.y);
        hx.p[1] = pkrtz(a.z, a.w);
        hx.p[2] = pkrtz(b.x, b.y);
        hx.p[3] = pkrtz(b.z, b.w);
        hx2.v = hx.v * hx.v;                       // packed f16 squares
        acc[0] = __builtin_amdgcn_mfma_f32_32x32x16_f16(
            hx2.v, sW8[(0*8 + ss)*64 + lane], acc[0], 0, 0, 0);
#pragma unroll
        for (int t = 1; t < 6; ++t)
          acc[t] = __builtin_amdgcn_mfma_f32_32x32x16_f16(
              hx.v, sW8[(t*8 + ss)*64 + lane], acc[t], 0, 0, 0);
      }
    }

    // ---- epilogue (C layout: col = c = component k; 16 regs = 16 rows) ----
    // u(row r, k=c) with folded constant
    float vp[16];
#pragma unroll
    for (int r = 0; r < 16; ++r)
      vp[r] = acc[1][r] - 0.5f*acc[0][r] + cc;

    // t2: e^2 packed, quad-reduce over l via DPP quad_perm (exact xor1/xor2)
    half2v tq[4][8];
#pragma unroll
    for (int zt = 0; zt < 4; ++zt)
#pragma unroll
      for (int i = 0; i < 8; ++i) {
        const float e0 = acc[2 + zt][2*i]     - hz[zt];
        const float e1 = acc[2 + zt][2*i + 1] - hz[zt];
        half2v p = pkrtz(e0*e0, e1*e1);
        p = p + dpp2<0xB1>(p);     // xor 1
        p = p + dpp2<0x4E>(p);     // xor 2
        tq[zt][i] = p;
      }
    // transport t2 to its k-owner lane (k = c): pull all 4 tile arrays from
    // srcl, select by zt* = c>>3
#pragma unroll
    for (int i = 0; i < 8; ++i) {
      half2v b0 = shl2(tq[0][i], srcl);
      half2v b1 = shl2(tq[1][i], srcl);
      half2v b2 = shl2(tq[2][i], srcl);
      half2v b3 = shl2(tq[3][i], srcl);
      half2v m01 = (c & 8)  ? b1 : b0;
      half2v m23 = (c & 8)  ? b3 : b2;
      half2v st  = (c & 16) ? m23 : m01;
      vp[2*i]     += 0.5f*(float)st[0];
      vp[2*i + 1] += 0.5f*(float)st[1];
    }

    // per-row max over the 32 k-lanes (packed fp16; DPP for xor1/2/4/8).
    // After quad-uniformity, row_half_mirror(xor7)==xor4 and
    // row_mirror(xor15)==xor8; xor16 crosses rows -> DS swizzle.
    half2v pm[8];
#pragma unroll
    for (int i = 0; i < 8; ++i)
      pm[i] = pkrtz(vp[2*i], vp[2*i + 1]);
#pragma unroll
    for (int i = 0; i < 8; ++i) {
      pm[i] = pmax2(pm[i], dpp2<0xB1>(pm[i]));
      pm[i] = pmax2(pm[i], dpp2<0x4E>(pm[i]));
      pm[i] = pmax2(pm[i], dpp2<0x141>(pm[i]));
      pm[i] = pmax2(pm[i], dpp2<0x140>(pm[i]));
      pm[i] = pmax2(pm[i], shx2(pm[i], 16));
    }

    // exp + packed sum reduction (same ladder)
    half2v ps[8];
#pragma unroll
    for (int i = 0; i < 8; ++i) {
      const float e0 = __expf(vp[2*i]     - (float)pm[i][0]);
      const float e1 = __expf(vp[2*i + 1] - (float)pm[i][1]);
      ps[i] = pkrtz(e0, e1);
    }
#pragma unroll
    for (int i = 0; i < 8; ++i) {
      ps[i] = ps[i] + dpp2<0xB1>(ps[i]);
      ps[i] = ps[i] + dpp2<0x4E>(ps[i]);
      ps[i] = ps[i] + dpp2<0x141>(ps[i]);
      ps[i] = ps[i] + dpp2<0x140>(ps[i]);
      ps[i] = ps[i] + shx2(ps[i], 16);
    }

    // write: lanes c<16 of each half cover the 32 rows
    if (c < 16) {
      const half2v S = sel8(ps, c >> 1);
      const half2v M = sel8(pm, c >> 1);
      const float sum = (c & 1) ? (float)S[1] : (float)S[0];
      const float mx  = (c & 1) ? (float)M[1] : (float)M[0];
      const int rw = tile*32 + (c & 3) + 8*(c >> 2) + 4*h;
      if (rw < N) out[rw] = mx + __logf(sum);
    }
  }
}

extern "C" void kernel_launch(void* const* d_in, const int* in_sizes, int n_in,
                              void* d_out, int out_size, void* d_ws, size_t ws_size,
                              hipStream_t stream) {
  const float* x  = (const float*)d_in[0];
  const float* MU = (const float*)d_in[1];
  const float* A  = (const float*)d_in[2];
  const float* D  = (const float*)d_in[3];
  const float* PI = (const float*)d_in[4];
  float* out = (float*)d_out;

  const int N = in_sizes[0] / DD;
  _Float16* wsw = (_Float16*)d_ws;
  float* wsc = (float*)((char*)d_ws + (size_t)NCOL*DD*sizeof(_Float16)); // +49152
  float* wsh = wsc + KC;            // 128 floats
  float* wsr = wsh + KC*LL;         // 512 floats (Ri)

  hipLaunchKernelGGL(mfa_woodbury, dim3(1), dim3(256), 0, stream,
                     MU, A, D, PI, wsc, wsh, wsr);
  hipLaunchKernelGGL(mfa_weights, dim3(96), dim3(256), 0, stream,
                     MU, A, D, wsr, wsw);

  const int ntiles = (N + 31) / 32;
  const int iters  = (ntiles + NSLOT - 1) / NSLOT;
  hipLaunchKernelGGL(mfa_main, dim3(NBLK), dim3(256), 0, stream,
                     x, wsw, wsc, wsh, out, N, ntiles, iters);
}